// Round 7
// baseline (5694.154 us; speedup 1.0000x reference)
//
#include <hip/hip_runtime.h>
#include <hip/hip_bf16.h>

// Bidirectional LSTM, B=32 T=512 D=H=512. f32 I/O, bf16 MFMA internally.
//
// R13 = R9's protocol/ordering VERBATIM, decomposition 64wg x 256t ->
//       32wg x 512t (each wg owns 32 h-cols, 8 waves).
//  - Evidence R10/R11/R12: every deviation from R9's step ordering loses.
//    Kept exactly: stage xnxt -> x(t+2) prefetch -> x-MFMAs -> poll(sweep,
//    wait, check, sleep) -> hA stage -> barrier C -> h-MFMAs -> vbuf ->
//    barrier D -> cell -> tagged h-store -> out-store.
//  - Halving wg count halves poll traffic (4MB->2MB/step of agent-scope
//    LLC reads) and the producer convoy tail (max over 16/dir not 32/dir);
//    per-thread sweep 32->16 loads (shallower vmcnt chain).
//  - Per-wave cost unchanged: 16 weight rows/wave (128 VGPR weights);
//    xp shrinks to 4 chunks (-32 VGPR), hv to [4][4] (-32 VGPR).
//  - Tagged 8B payload exchange (R9): tag=step+1 hi-dword, payload=2 bf16.
//    Poll = dense batched re-sweep. 2 lgkm-only barriers/step.

typedef __bf16 bf16;
typedef __attribute__((ext_vector_type(8))) __bf16 bf16x8;
typedef __attribute__((ext_vector_type(4))) float f32x4;
typedef __attribute__((ext_vector_type(4))) unsigned u32x4;
typedef unsigned long long u64;

__device__ __forceinline__ float sigmoidf_(float x) {
  return 1.f / (1.f + __expf(-x));
}
__device__ __forceinline__ float tanhf_(float x) {
  float e = __expf(-2.f * fabsf(x));
  return copysignf((1.f - e) / (1.f + e), x);
}
__device__ __forceinline__ u64 ald64(const u64* p) {
  return __hip_atomic_load(p, __ATOMIC_RELAXED, __HIP_MEMORY_SCOPE_AGENT);
}
__device__ __forceinline__ void ast64(u64* p, u64 v) {
  __hip_atomic_store(p, v, __ATOMIC_RELAXED, __HIP_MEMORY_SCOPE_AGENT);
}
__device__ __forceinline__ bf16x8 cvt8v(float4 a, float4 b) {
  bf16x8 v;
  v[0] = (bf16)a.x; v[1] = (bf16)a.y; v[2] = (bf16)a.z; v[3] = (bf16)a.w;
  v[4] = (bf16)b.x; v[5] = (bf16)b.y; v[6] = (bf16)b.z; v[7] = (bf16)b.w;
  return v;
}
// Barrier with LDS-visibility only: does NOT drain vmcnt, so in-flight
// global loads survive across it.
__device__ __forceinline__ void bar_lgkm() {
  asm volatile("s_waitcnt lgkmcnt(0)\n\ts_barrier" ::: "memory");
}

// ---------------- lengths ----------------
__global__ void lengths_kernel(const int* __restrict__ mask, int* __restrict__ lengths) {
  __shared__ int part[32][8];
  int t = threadIdx.x;
  int b = t >> 3, sub = t & 7;
  int s = 0;
#pragma unroll 8
  for (int k = 0; k < 64; ++k) s += mask[b * 512 + sub + 8 * k];
  part[b][sub] = s;
  __syncthreads();
  if (sub == 0) {
    int tot = 0;
#pragma unroll
    for (int k = 0; k < 8; ++k) tot += part[b][k];
    lengths[b] = tot;
  }
}

// ---------------- fused persistent LSTM ----------------
__global__ __launch_bounds__(512, 1) void lstm_fused(
    const float* __restrict__ x,                                  // [32][512][512] f32
    const float* __restrict__ Wih_f, const float* __restrict__ bih_f,
    const float* __restrict__ Whh_f,
    const float* __restrict__ Wih_b, const float* __restrict__ bih_b,
    const float* __restrict__ Whh_b,
    const int* __restrict__ lengths,
    u64* __restrict__ hbuf,             // [2 dir][2 par][32 batch][256] u64 entries
    float* __restrict__ out) {          // [32][512][1024] f32
  const int s = blockIdx.x;             // h-col slice: cols [32s, 32s+32)
  const int dir = blockIdx.y;
  const float* Wih = dir ? Wih_b : Wih_f;
  const float* Whh = dir ? Whh_b : Whh_f;
  const float* bih = dir ? bih_b : bih_f;

  const int tid = threadIdx.x;
  const int lane = tid & 63, wave = tid >> 6;   // wave in [0,8)
  const int l15 = lane & 15, quad = lane >> 4;

  __shared__ __align__(16) bf16 xA[2][32 * 512];  // 2x32 KB x double buffer
  __shared__ __align__(16) bf16 hA[32 * 512];     // 32 KB h (single)
  __shared__ float vbuf[4][32][33];               // [gate][batch][colInSlice]
  __shared__ int lenL[32];

  // Wave w owns 16 weight rows: gate = w>>1, colInSlice = (w&1)*16 + l15.
  const int grow = (wave >> 1) * 512 + s * 32 + (wave & 1) * 16 + l15;

  bf16x8 wih[16], whh[16];
#pragma unroll
  for (int k = 0; k < 16; ++k) {
    const float* pw = Wih + (size_t)grow * 512 + k * 32 + quad * 8;
    const float* ph = Whh + (size_t)grow * 512 + k * 32 + quad * 8;
    wih[k] = cvt8v(*(const float4*)pw, *(const float4*)(pw + 4));
    whh[k] = cvt8v(*(const float4*)ph, *(const float4*)(ph + 4));
  }
  const float bv = bih[grow];
  if (tid < 32) lenL[tid] = lengths[tid];
  __syncthreads();

  // Cell/store mapping: 512 threads; cb = batch, cj = col pair in [0,32).
  const int cb = tid >> 4, cj = (tid & 15) * 2;
  int lenR[4];
#pragma unroll
  for (int i = 0; i < 4; ++i) lenR[i] = lenL[(i * 512 + tid) >> 6];
  const int lenO = lenL[cb];

  float creg0 = 0.f, creg1 = 0.f;
  u64* hb = hbuf + (size_t)dir * (2 * 32 * 256);

  // Prologue: load x(0), stage xA[0], then issue prefetch of x(1).
  float4 xp[4][2];
#pragma unroll
  for (int i = 0; i < 4; ++i) {
    int c = i * 512 + tid;
    int m = c >> 6, kbp = c & 63;
    int kb = kbp ^ (m & 7);
    int tr = (dir == 0) ? 0 : ((511 + lenR[i]) & 511);
    const float4* p = (const float4*)(x + ((size_t)m * 512 + tr) * 512 + kb * 8);
    xp[i][0] = p[0]; xp[i][1] = p[1];
  }
#pragma unroll
  for (int i = 0; i < 4; ++i) {
    int c = i * 512 + tid;
    *(bf16x8*)(xA[0] + c * 8) = cvt8v(xp[i][0], xp[i][1]);
  }
#pragma unroll
  for (int i = 0; i < 4; ++i) {
    int c = i * 512 + tid;
    int m = c >> 6, kbp = c & 63;
    int kb = kbp ^ (m & 7);
    int tr = (dir == 0) ? 1 : ((510 + lenR[i]) & 511);
    const float4* p = (const float4*)(x + ((size_t)m * 512 + tr) * 512 + kb * 8);
    xp[i][0] = p[0]; xp[i][1] = p[1];
  }
  bar_lgkm();  // xA[0] staged

  for (int step = 0; step < 512; ++step) {
    const int par = step & 1;
    const u64* hprev = hb + (size_t)par * (32 * 256);
    u64* hnext = hb + (size_t)(par ^ 1) * (32 * 256);
    const bf16* xcur = xA[par];
    bf16* xnxt = xA[par ^ 1];

    // ---- (1) stage xA(t+1) from regs ----
    if (step < 511) {
#pragma unroll
      for (int i = 0; i < 4; ++i) {
        int c = i * 512 + tid;
        *(bf16x8*)(xnxt + c * 8) = cvt8v(xp[i][0], xp[i][1]);
      }
    }
    // ---- (2) x(t+2) prefetch issue (R9 position: before MFMAs) ----
    if (step < 510) {
#pragma unroll
      for (int i = 0; i < 4; ++i) {
        int c = i * 512 + tid;
        int m = c >> 6, kbp = c & 63;
        int kb = kbp ^ (m & 7);
        int tr = (dir == 0) ? (step + 2) : ((509 - step + lenR[i]) & 511);
        const float4* p = (const float4*)(x + ((size_t)m * 512 + tr) * 512 + kb * 8);
        xp[i][0] = p[0]; xp[i][1] = p[1];
      }
    }

    // ---- (3) x-part MFMAs: v = x@Wih^T + bias ----
    f32x4 acc0 = {bv, bv, bv, bv};
    f32x4 acc1 = {bv, bv, bv, bv};
#pragma unroll
    for (int k = 0; k < 16; ++k) {
      int kb = k * 4 + quad;
      int sw = (kb ^ (l15 & 7)) * 8;
      bf16x8 ax0 = *(const bf16x8*)(xcur + l15 * 512 + sw);
      bf16x8 ax1 = *(const bf16x8*)(xcur + (16 + l15) * 512 + sw);
      acc0 = __builtin_amdgcn_mfma_f32_16x16x32_bf16(ax0, wih[k], acc0, 0, 0, 0);
      acc1 = __builtin_amdgcn_mfma_f32_16x16x32_bf16(ax1, wih[k], acc1, 0, 0, 0);
    }
    __builtin_amdgcn_sched_barrier(0);

    // ---- (4) poll (R9 position): wave w covers batches [4w,4w+4);
    //      lane owns entries [4*lane, 4*lane+4). Dense batched re-sweep.
    u64 hv[4][4];
    {
      const unsigned target = (unsigned)step;
      while (true) {
#pragma unroll
        for (int b = 0; b < 4; ++b) {
          const u64* rp = hprev + (wave * 4 + b) * 256 + 4 * lane;
#pragma unroll
          for (int j = 0; j < 4; ++j) hv[b][j] = ald64(rp + j);
        }
        int ok = 1;
#pragma unroll
        for (int b = 0; b < 4; ++b)
#pragma unroll
          for (int j = 0; j < 4; ++j)
            ok &= (int)((unsigned)(hv[b][j] >> 32) >= target);
        if (__all(ok)) break;
        __builtin_amdgcn_s_sleep(1);
      }
    }

    // ---- (5) stage payloads -> swizzled hA (one b128 per batch) ----
#pragma unroll
    for (int b = 0; b < 4; ++b) {
      int m = wave * 4 + b;
      u32x4 blk = {(unsigned)hv[b][0], (unsigned)hv[b][1],
                   (unsigned)hv[b][2], (unsigned)hv[b][3]};
      *(u32x4*)(hA + m * 512 + ((lane ^ (m & 7)) * 8)) = blk;
    }
    bar_lgkm();  // C: hA + xnxt visible (x prefetch rides through)

    // ---- (6) h-part MFMAs: v += h@Whh^T ----
#pragma unroll
    for (int k = 0; k < 16; ++k) {
      int kb = k * 4 + quad;
      int sw = (kb ^ (l15 & 7)) * 8;
      bf16x8 ah0 = *(const bf16x8*)(hA + l15 * 512 + sw);
      bf16x8 ah1 = *(const bf16x8*)(hA + (16 + l15) * 512 + sw);
      acc0 = __builtin_amdgcn_mfma_f32_16x16x32_bf16(ah0, whh[k], acc0, 0, 0, 0);
      acc1 = __builtin_amdgcn_mfma_f32_16x16x32_bf16(ah1, whh[k], acc1, 0, 0, 0);
    }
#pragma unroll
    for (int r = 0; r < 4; ++r) {
      vbuf[wave >> 1][quad * 4 + r][(wave & 1) * 16 + l15] = acc0[r];
      vbuf[wave >> 1][16 + quad * 4 + r][(wave & 1) * 16 + l15] = acc1[r];
    }
    bar_lgkm();  // D: vbuf ready

    // ---- (7) cell update ----
    float i0 = vbuf[0][cb][cj],     f0 = vbuf[1][cb][cj];
    float g0 = vbuf[2][cb][cj],     o0 = vbuf[3][cb][cj];
    float i1 = vbuf[0][cb][cj + 1], f1 = vbuf[1][cb][cj + 1];
    float g1 = vbuf[2][cb][cj + 1], o1 = vbuf[3][cb][cj + 1];
    float c0 = sigmoidf_(f0) * creg0 + sigmoidf_(i0) * tanhf_(g0);
    float c1 = sigmoidf_(f1) * creg1 + sigmoidf_(i1) * tanhf_(g1);
    creg0 = c0; creg1 = c1;
    float h0 = tanhf_(c0) * sigmoidf_(o0);
    float h1 = tanhf_(c1) * sigmoidf_(o1);

    // ---- (8) tagged h store: 128B contiguous per 16-thread group ----
    unsigned ulo = (unsigned)__builtin_bit_cast(unsigned short, (bf16)h0);
    unsigned uhi = (unsigned)__builtin_bit_cast(unsigned short, (bf16)h1);
    u64 pk = ((u64)(unsigned)(step + 1) << 32) | (u64)(ulo | (uhi << 16));
    ast64(hnext + cb * 256 + s * 16 + (tid & 15), pk);   // fire and forget

    // ---- (9) out store (128B contiguous per 16-thread group) ----
    int tr = (dir == 0) ? step : ((511 - step + lenO) & 511);
    *(float2*)(out + (size_t)(cb * 512 + tr) * 1024 + dir * 512 + s * 32 + cj) =
        make_float2(h0, h1);
  }
}

extern "C" void kernel_launch(void* const* d_in, const int* in_sizes, int n_in,
                              void* d_out, int out_size, void* d_ws, size_t ws_size,
                              hipStream_t stream) {
  (void)in_sizes; (void)n_in; (void)out_size; (void)ws_size;
  const float* x    = (const float*)d_in[0];
  const int*   mask = (const int*)  d_in[1];
  const float* Wihf = (const float*)d_in[2];
  const float* bihf = (const float*)d_in[3];
  const float* Whhf = (const float*)d_in[4];
  const float* Wihb = (const float*)d_in[5];
  const float* bihb = (const float*)d_in[6];
  const float* Whhb = (const float*)d_in[7];
  float* out = (float*)d_out;

  char* ws = (char*)d_ws;
  u64* hbuf = (u64*)ws;                          // 2*2*32*256*8 = 262144 B
  int* lengths = (int*)(ws + 262144);            // 128 B
  const size_t head = 262144;

  hipMemsetAsync(d_ws, 0, head, stream);  // zero tags + h0 = c0 = 0 every call
  lengths_kernel<<<1, 256, 0, stream>>>(mask, lengths);
  lstm_fused<<<dim3(16, 2), 512, 0, stream>>>(
      x, Wihf, bihf, Whhf, Wihb, bihb, Whhb, lengths, hbuf, out);
}

// Round 8
// 2357.935 us; speedup vs baseline: 2.4149x; 2.4149x over previous
//
#include <hip/hip_runtime.h>
#include <hip/hip_bf16.h>

// Bidirectional LSTM, B=32 T=512 D=H=512. f32 I/O, bf16 MFMA internally.
//
// R14 = R9 (best measured: 2110us) with ONE change: two-phase poll.
//  - Phase A: sentinel spin — 1 tagged entry per batch (8 loads/thread,
//    4x fewer LLC line-touches per retry than the full 32-load sweep).
//    Producer wave w of wg s writes a consumer lane's 4 entries of a batch
//    in one instruction, so one sentinel per batch tracks readiness well.
//  - Phase B: full dense 32-load sweep with PER-ENTRY tag verification
//    (correctness never relies on intra-line visibility order; a stale
//    entry after sentinel-pass just loops the verified sweep — rare).
//  - Everything else verbatim R9: grid=(32,2)x256, tagged 8B payload
//    exchange, step ordering {stage xnxt, x(t+2) prefetch, x-MFMAs, poll,
//    hA stage, barrier C, h-MFMAs, vbuf, barrier D, cell, coalesced tagged
//    h-store, coalesced out-store}, 2 lgkm-only barriers/step.
//  - Lessons encoded: R10 (no masked/serialized loads), R11/R12 (no
//    reordering of R9's step; early sweep is guaranteed-stale), R13 (4
//    waves x 256t keeps weights in 128 VGPRs without allocator fights).

typedef __bf16 bf16;
typedef __attribute__((ext_vector_type(8))) __bf16 bf16x8;
typedef __attribute__((ext_vector_type(4))) float f32x4;
typedef __attribute__((ext_vector_type(4))) unsigned u32x4;
typedef unsigned long long u64;

__device__ __forceinline__ float sigmoidf_(float x) {
  return 1.f / (1.f + __expf(-x));
}
__device__ __forceinline__ float tanhf_(float x) {
  float e = __expf(-2.f * fabsf(x));
  return copysignf((1.f - e) / (1.f + e), x);
}
__device__ __forceinline__ u64 ald64(const u64* p) {
  return __hip_atomic_load(p, __ATOMIC_RELAXED, __HIP_MEMORY_SCOPE_AGENT);
}
__device__ __forceinline__ void ast64(u64* p, u64 v) {
  __hip_atomic_store(p, v, __ATOMIC_RELAXED, __HIP_MEMORY_SCOPE_AGENT);
}
__device__ __forceinline__ bf16x8 cvt8v(float4 a, float4 b) {
  bf16x8 v;
  v[0] = (bf16)a.x; v[1] = (bf16)a.y; v[2] = (bf16)a.z; v[3] = (bf16)a.w;
  v[4] = (bf16)b.x; v[5] = (bf16)b.y; v[6] = (bf16)b.z; v[7] = (bf16)b.w;
  return v;
}
// Barrier with LDS-visibility only: does NOT drain vmcnt, so in-flight
// global loads survive across it.
__device__ __forceinline__ void bar_lgkm() {
  asm volatile("s_waitcnt lgkmcnt(0)\n\ts_barrier" ::: "memory");
}

// ---------------- lengths ----------------
__global__ void lengths_kernel(const int* __restrict__ mask, int* __restrict__ lengths) {
  __shared__ int part[32][8];
  int t = threadIdx.x;
  int b = t >> 3, sub = t & 7;
  int s = 0;
#pragma unroll 8
  for (int k = 0; k < 64; ++k) s += mask[b * 512 + sub + 8 * k];
  part[b][sub] = s;
  __syncthreads();
  if (sub == 0) {
    int tot = 0;
#pragma unroll
    for (int k = 0; k < 8; ++k) tot += part[b][k];
    lengths[b] = tot;
  }
}

// ---------------- fused persistent LSTM ----------------
__global__ __launch_bounds__(256, 1) void lstm_fused(
    const float* __restrict__ x,                                  // [32][512][512] f32
    const float* __restrict__ Wih_f, const float* __restrict__ bih_f,
    const float* __restrict__ Whh_f,
    const float* __restrict__ Wih_b, const float* __restrict__ bih_b,
    const float* __restrict__ Whh_b,
    const int* __restrict__ lengths,
    u64* __restrict__ hbuf,             // [2 dir][2 par][32 batch][256] u64 entries
    float* __restrict__ out) {          // [32][512][1024] f32
  const int s = blockIdx.x;             // h-col slice: cols [16s, 16s+16)
  const int dir = blockIdx.y;
  const float* Wih = dir ? Wih_b : Wih_f;
  const float* Whh = dir ? Whh_b : Whh_f;
  const float* bih = dir ? bih_b : bih_f;

  const int tid = threadIdx.x;
  const int lane = tid & 63, wave = tid >> 6;
  const int l15 = lane & 15, quad = lane >> 4;

  __shared__ __align__(16) bf16 xA[2][32 * 512];  // 2x32 KB x double buffer
  __shared__ __align__(16) bf16 hA[32 * 512];     // 32 KB h (single)
  __shared__ float vbuf[4][32][17];
  __shared__ int lenL[32];

  // Weight slices f32 -> bf16 registers (wave = gate; B-frag n=l15).
  bf16x8 wih[16], whh[16];
  {
    int grow = wave * 512 + s * 16 + l15;
#pragma unroll
    for (int k = 0; k < 16; ++k) {
      const float* pw = Wih + (size_t)grow * 512 + k * 32 + quad * 8;
      const float* ph = Whh + (size_t)grow * 512 + k * 32 + quad * 8;
      wih[k] = cvt8v(*(const float4*)pw, *(const float4*)(pw + 4));
      whh[k] = cvt8v(*(const float4*)ph, *(const float4*)(ph + 4));
    }
  }
  const float bv = bih[wave * 512 + s * 16 + l15];
  if (tid < 32) lenL[tid] = lengths[tid];
  __syncthreads();

  const int cb = tid >> 3, cj = (tid & 7) * 2;
  int lenR[8];
#pragma unroll
  for (int i = 0; i < 8; ++i) lenR[i] = lenL[(i * 256 + tid) >> 6];
  const int lenO = lenL[cb];

  float creg0 = 0.f, creg1 = 0.f;
  u64* hb = hbuf + (size_t)dir * (2 * 32 * 256);

  // Prologue: load x(0), stage xA[0], then issue prefetch of x(1).
  float4 xp[8][2];
#pragma unroll
  for (int i = 0; i < 8; ++i) {
    int c = i * 256 + tid;
    int m = c >> 6, kbp = c & 63;
    int kb = kbp ^ (m & 7);
    int tr = (dir == 0) ? 0 : ((511 + lenR[i]) & 511);
    const float4* p = (const float4*)(x + ((size_t)m * 512 + tr) * 512 + kb * 8);
    xp[i][0] = p[0]; xp[i][1] = p[1];
  }
#pragma unroll
  for (int i = 0; i < 8; ++i) {
    int c = i * 256 + tid;
    *(bf16x8*)(xA[0] + c * 8) = cvt8v(xp[i][0], xp[i][1]);
  }
#pragma unroll
  for (int i = 0; i < 8; ++i) {
    int c = i * 256 + tid;
    int m = c >> 6, kbp = c & 63;
    int kb = kbp ^ (m & 7);
    int tr = (dir == 0) ? 1 : ((510 + lenR[i]) & 511);
    const float4* p = (const float4*)(x + ((size_t)m * 512 + tr) * 512 + kb * 8);
    xp[i][0] = p[0]; xp[i][1] = p[1];
  }
  bar_lgkm();  // xA[0] staged

  for (int step = 0; step < 512; ++step) {
    const int par = step & 1;
    const u64* hprev = hb + (size_t)par * (32 * 256);
    u64* hnext = hb + (size_t)(par ^ 1) * (32 * 256);
    const bf16* xcur = xA[par];
    bf16* xnxt = xA[par ^ 1];

    // ---- (1) stage xA(t+1) from regs ----
    if (step < 511) {
#pragma unroll
      for (int i = 0; i < 8; ++i) {
        int c = i * 256 + tid;
        *(bf16x8*)(xnxt + c * 8) = cvt8v(xp[i][0], xp[i][1]);
      }
    }
    // ---- (2) x(t+2) prefetch issue (R9 position) ----
    if (step < 510) {
#pragma unroll
      for (int i = 0; i < 8; ++i) {
        int c = i * 256 + tid;
        int m = c >> 6, kbp = c & 63;
        int kb = kbp ^ (m & 7);
        int tr = (dir == 0) ? (step + 2) : ((509 - step + lenR[i]) & 511);
        const float4* p = (const float4*)(x + ((size_t)m * 512 + tr) * 512 + kb * 8);
        xp[i][0] = p[0]; xp[i][1] = p[1];
      }
    }

    // ---- (3) x-part MFMAs: v = x@Wih^T + bias ----
    f32x4 acc0 = {bv, bv, bv, bv};
    f32x4 acc1 = {bv, bv, bv, bv};
#pragma unroll
    for (int k = 0; k < 16; ++k) {
      int kb = k * 4 + quad;
      int sw = (kb ^ (l15 & 7)) * 8;
      bf16x8 ax0 = *(const bf16x8*)(xcur + l15 * 512 + sw);
      bf16x8 ax1 = *(const bf16x8*)(xcur + (16 + l15) * 512 + sw);
      acc0 = __builtin_amdgcn_mfma_f32_16x16x32_bf16(ax0, wih[k], acc0, 0, 0, 0);
      acc1 = __builtin_amdgcn_mfma_f32_16x16x32_bf16(ax1, wih[k], acc1, 0, 0, 0);
    }
    __builtin_amdgcn_sched_barrier(0);

    // ---- (4) two-phase poll (R9 position) ----
    // wave w covers batches [8w,8w+8); lane owns entries [4*lane,4*lane+4).
    u64 hv[8][4];
    {
      const unsigned target = (unsigned)step;
      // Phase A: sentinel spin — 1 entry per batch (cheap retries).
      while (true) {
        u64 sv[8];
#pragma unroll
        for (int b = 0; b < 8; ++b)
          sv[b] = ald64(hprev + (wave * 8 + b) * 256 + 4 * lane);
        int ok = 1;
#pragma unroll
        for (int b = 0; b < 8; ++b)
          ok &= (int)((unsigned)(sv[b] >> 32) >= target);
        if (__all(ok)) break;
        __builtin_amdgcn_s_sleep(1);
      }
      // Phase B: full dense sweep + per-entry verify (usually one pass).
      while (true) {
#pragma unroll
        for (int b = 0; b < 8; ++b) {
          const u64* rp = hprev + (wave * 8 + b) * 256 + 4 * lane;
#pragma unroll
          for (int j = 0; j < 4; ++j) hv[b][j] = ald64(rp + j);
        }
        int ok = 1;
#pragma unroll
        for (int b = 0; b < 8; ++b)
#pragma unroll
          for (int j = 0; j < 4; ++j)
            ok &= (int)((unsigned)(hv[b][j] >> 32) >= target);
        if (__all(ok)) break;
        __builtin_amdgcn_s_sleep(1);
      }
    }

    // ---- (5) stage payloads -> swizzled hA (one b128 per batch) ----
#pragma unroll
    for (int b = 0; b < 8; ++b) {
      int m = wave * 8 + b;
      u32x4 blk = {(unsigned)hv[b][0], (unsigned)hv[b][1],
                   (unsigned)hv[b][2], (unsigned)hv[b][3]};
      *(u32x4*)(hA + m * 512 + ((lane ^ (m & 7)) * 8)) = blk;
    }
    bar_lgkm();  // C: hA + xnxt visible (x prefetch rides through)

    // ---- (6) h-part MFMAs: v += h@Whh^T ----
#pragma unroll
    for (int k = 0; k < 16; ++k) {
      int kb = k * 4 + quad;
      int sw = (kb ^ (l15 & 7)) * 8;
      bf16x8 ah0 = *(const bf16x8*)(hA + l15 * 512 + sw);
      bf16x8 ah1 = *(const bf16x8*)(hA + (16 + l15) * 512 + sw);
      acc0 = __builtin_amdgcn_mfma_f32_16x16x32_bf16(ah0, whh[k], acc0, 0, 0, 0);
      acc1 = __builtin_amdgcn_mfma_f32_16x16x32_bf16(ah1, whh[k], acc1, 0, 0, 0);
    }
#pragma unroll
    for (int r = 0; r < 4; ++r) {
      vbuf[wave][quad * 4 + r][l15] = acc0[r];
      vbuf[wave][16 + quad * 4 + r][l15] = acc1[r];
    }
    bar_lgkm();  // D: vbuf ready

    // ---- (7) cell update ----
    float i0 = vbuf[0][cb][cj],     f0 = vbuf[1][cb][cj];
    float g0 = vbuf[2][cb][cj],     o0 = vbuf[3][cb][cj];
    float i1 = vbuf[0][cb][cj + 1], f1 = vbuf[1][cb][cj + 1];
    float g1 = vbuf[2][cb][cj + 1], o1 = vbuf[3][cb][cj + 1];
    float c0 = sigmoidf_(f0) * creg0 + sigmoidf_(i0) * tanhf_(g0);
    float c1 = sigmoidf_(f1) * creg1 + sigmoidf_(i1) * tanhf_(g1);
    creg0 = c0; creg1 = c1;
    float h0 = tanhf_(c0) * sigmoidf_(o0);
    float h1 = tanhf_(c1) * sigmoidf_(o1);

    // ---- (8) tagged h store: coalesced 64B line per 8 lanes of one wave ----
    unsigned ulo = (unsigned)__builtin_bit_cast(unsigned short, (bf16)h0);
    unsigned uhi = (unsigned)__builtin_bit_cast(unsigned short, (bf16)h1);
    u64 pk = ((u64)(unsigned)(step + 1) << 32) | (u64)(ulo | (uhi << 16));
    ast64(hnext + cb * 256 + s * 8 + (tid & 7), pk);   // fire and forget

    // ---- (9) out store (coalesced 64B per 8-thread group) ----
    int tr = (dir == 0) ? step : ((511 - step + lenO) & 511);
    *(float2*)(out + (size_t)(cb * 512 + tr) * 1024 + dir * 512 + s * 16 + cj) =
        make_float2(h0, h1);
  }
}

extern "C" void kernel_launch(void* const* d_in, const int* in_sizes, int n_in,
                              void* d_out, int out_size, void* d_ws, size_t ws_size,
                              hipStream_t stream) {
  (void)in_sizes; (void)n_in; (void)out_size; (void)ws_size;
  const float* x    = (const float*)d_in[0];
  const int*   mask = (const int*)  d_in[1];
  const float* Wihf = (const float*)d_in[2];
  const float* bihf = (const float*)d_in[3];
  const float* Whhf = (const float*)d_in[4];
  const float* Wihb = (const float*)d_in[5];
  const float* bihb = (const float*)d_in[6];
  const float* Whhb = (const float*)d_in[7];
  float* out = (float*)d_out;

  char* ws = (char*)d_ws;
  u64* hbuf = (u64*)ws;                          // 2*2*32*256*8 = 262144 B
  int* lengths = (int*)(ws + 262144);            // 128 B
  const size_t head = 262144;

  hipMemsetAsync(d_ws, 0, head, stream);  // zero tags + h0 = c0 = 0 every call
  lengths_kernel<<<1, 256, 0, stream>>>(mask, lengths);
  lstm_fused<<<dim3(32, 2), 256, 0, stream>>>(
      x, Wihf, bihf, Whhf, Wihb, bihb, Whhb, lengths, hbuf, out);
}